// Round 2
// baseline (10996.086 us; speedup 1.0000x reference)
//
#include <hip/hip_runtime.h>
#include <hip/hip_bf16.h>

#define DEV __device__ __forceinline__

typedef __attribute__((ext_vector_type(4))) float f32x4;
typedef __bf16 bf16x8 __attribute__((ext_vector_type(8)));

static DEV unsigned short f2bf(float f) {
    union { float f; unsigned u; } x; x.f = f;
    unsigned r = x.u + 0x7fffu + ((x.u >> 16) & 1u);
    return (unsigned short)(r >> 16);
}

static DEV unsigned pack2bf(float a, float b) {
    return (unsigned)f2bf(a) | ((unsigned)f2bf(b) << 16);
}

static DEV f32x4 zero4() { f32x4 v; v[0] = 0.f; v[1] = 0.f; v[2] = 0.f; v[3] = 0.f; return v; }

// ---------------- conversion kernels ----------------

__global__ void k_cvt_bf16(const float* __restrict__ in, unsigned short* __restrict__ out, int n4) {
    int i = blockIdx.x * blockDim.x + threadIdx.x;
    if (i >= n4) return;
    float4 v = reinterpret_cast<const float4*>(in)[i];
    ushort4 o;
    o.x = f2bf(v.x); o.y = f2bf(v.y); o.z = f2bf(v.z); o.w = f2bf(v.w);
    reinterpret_cast<ushort4*>(out)[i] = o;
}

// in [K][N] f32 -> out [N][K] bf16
__global__ void k_transpose_bf16(const float* __restrict__ in, unsigned short* __restrict__ out, int K, int N) {
    int i = blockIdx.x * blockDim.x + threadIdx.x;
    if (i >= K * N) return;
    int n = i / K, k = i - n * K;
    out[i] = f2bf(in[(size_t)k * N + n]);
}

// ---------------- GEMM: C[M,N] = A[M,384] * B^T  (B stored [N][384]) ----------------

template <int EPI>
__global__ __launch_bounds__(256) void k_gemm(
    const unsigned short* __restrict__ A,
    const unsigned short* __restrict__ B,
    unsigned short* __restrict__ Qb, unsigned short* __restrict__ Kb, unsigned short* __restrict__ Vtb,
    const float* __restrict__ bias, float* __restrict__ Out)
{
    const int K = 384;
    __shared__ unsigned short lA[128][72];
    __shared__ unsigned short lB[128][72];

    int tid = threadIdx.x;
    int m0 = blockIdx.x * 128;
    int n0 = blockIdx.y * 128;
    int w = tid >> 6, lane = tid & 63;
    int wm = (w >> 1) * 64, wn = (w & 1) * 64;
    int lr = lane & 15, lg = lane >> 4;

    f32x4 acc[4][4];
#pragma unroll
    for (int i = 0; i < 4; i++)
#pragma unroll
        for (int j = 0; j < 4; j++) acc[i][j] = zero4();

    int srow = tid >> 3, scol = (tid & 7) * 8;

    for (int kb = 0; kb < K; kb += 64) {
        __syncthreads();
#pragma unroll
        for (int p = 0; p < 4; ++p) {
            int r = srow + p * 32;
            *(uint4*)&lA[r][scol] = *(const uint4*)&A[(size_t)(m0 + r) * K + kb + scol];
            *(uint4*)&lB[r][scol] = *(const uint4*)&B[(size_t)(n0 + r) * K + kb + scol];
        }
        __syncthreads();

        bf16x8 af[4][2], bfr[4][2];
#pragma unroll
        for (int kc = 0; kc < 2; ++kc) {
#pragma unroll
            for (int t = 0; t < 4; ++t) {
                af[t][kc]  = *(const bf16x8*)&lA[wm + t * 16 + lr][kc * 32 + lg * 8];
                bfr[t][kc] = *(const bf16x8*)&lB[wn + t * 16 + lr][kc * 32 + lg * 8];
            }
        }
#pragma unroll
        for (int kc = 0; kc < 2; ++kc)
#pragma unroll
            for (int mt = 0; mt < 4; ++mt)
#pragma unroll
                for (int nt = 0; nt < 4; ++nt)
                    acc[mt][nt] = __builtin_amdgcn_mfma_f32_16x16x32_bf16(af[mt][kc], bfr[nt][kc], acc[mt][nt], 0, 0, 0);
    }

#pragma unroll
    for (int mt = 0; mt < 4; ++mt) {
#pragma unroll
        for (int nt = 0; nt < 4; ++nt) {
#pragma unroll
            for (int r = 0; r < 4; ++r) {
                int row = m0 + wm + mt * 16 + lg * 4 + r;
                int col = n0 + wn + nt * 16 + lr;
                float v = acc[mt][nt][r];
                if (EPI == 0) {
                    int which = col / 384;
                    int c = col - which * 384;
                    int hh = c >> 6, d = c & 63;
                    int bb = row >> 10, t = row & 1023;
                    size_t bh = (size_t)bb * 6 + hh;
                    if (which == 0)      Qb[(bh * 1024 + t) * 64 + d] = f2bf(v * 0.125f);
                    else if (which == 1) Kb[(bh * 1024 + t) * 64 + d] = f2bf(v);
                    else                 Vtb[(bh * 64 + d) * 1024 + t] = f2bf(v);
                } else {
                    Out[(size_t)row * 384 + col] = v + bias[col];
                }
            }
        }
    }
}

// ---------------- flash attention, fixed-max, no block barriers ----------------
// grid (48 bh-groups, 32 qtiles); block 256 = 4 waves; wave w handles bh = bx*4+w,
// q-rows [qt*32, qt*32+32). K,V fragments read directly from global (L2-resident).
__global__ __launch_bounds__(256) void k_attn(
    const unsigned short* __restrict__ Q,
    const unsigned short* __restrict__ Kp,
    const unsigned short* __restrict__ Vt,
    unsigned short* __restrict__ Y)
{
    __shared__ unsigned short lP[4][32][72];

    const int tid = threadIdx.x;
    const int w = tid >> 6, lane = tid & 63;
    const int lr = lane & 15, lg = lane >> 4;
    const int qt = 31 - blockIdx.y;          // heaviest q-tiles dispatched first
    const int bh = blockIdx.x * 4 + w;
    const int b = bh / 6, h = bh - b * 6;
    const int qw = qt * 32;
    const size_t bT = (size_t)bh * 1024;

    bf16x8 qf[2][2];
#pragma unroll
    for (int mt = 0; mt < 2; ++mt)
#pragma unroll
        for (int kc = 0; kc < 2; ++kc)
            qf[mt][kc] = *(const bf16x8*)&Q[(bT + qw + mt * 16 + lr) * 64 + kc * 32 + lg * 8];

    f32x4 o[2][4];
    float ls[2] = {0.f, 0.f};
#pragma unroll
    for (int mt = 0; mt < 2; ++mt)
#pragma unroll
        for (int nt = 0; nt < 4; ++nt) o[mt][nt] = zero4();

    const int nkt = (qw >> 6) + 1;
    for (int kt = 0; kt < nkt; ++kt) {
        const int rem = qw + 31 - kt * 64;
        const int ntm = (rem >= 48) ? 4 : ((rem >> 4) + 1);
        const int kcm = (ntm > 2) ? 2 : 1;
        const bool last = (kt == nkt - 1);

        // K fragments (A-operand of S^T) -- contiguous 16B per lane
        bf16x8 kf[4][2];
        for (int nt = 0; nt < ntm; ++nt)
#pragma unroll
            for (int kc = 0; kc < 2; ++kc)
                kf[nt][kc] = *(const bf16x8*)&Kp[(bT + kt * 64 + nt * 16 + lr) * 64 + kc * 32 + lg * 8];

        // V fragments (B-operand of PV) -- contiguous 16B per lane from V^T
        bf16x8 vf[4][2];
#pragma unroll
        for (int nt = 0; nt < 4; ++nt)
            for (int kc = 0; kc < kcm; ++kc)
                vf[nt][kc] = *(const bf16x8*)&Vt[((size_t)bh * 64 + nt * 16 + lr) * 1024 + kt * 64 + kc * 32 + lg * 8];

        // S^T = K * Q^T : lane holds col=q(lr), rows=k(lg*4+r), per 16-k subtile nt
        f32x4 st[2][4];
        for (int nt = 0; nt < ntm; ++nt) { st[0][nt] = zero4(); st[1][nt] = zero4(); }
#pragma unroll
        for (int kc = 0; kc < 2; ++kc)
#pragma unroll
            for (int mt = 0; mt < 2; ++mt)
                for (int nt = 0; nt < ntm; ++nt)
                    st[mt][nt] = __builtin_amdgcn_mfma_f32_16x16x32_bf16(kf[nt][kc], qf[mt][kc], st[mt][nt], 0, 0, 0);

        // exp (fixed max), per-lane partial rowsum, pack to bf16, vector LDS write
#pragma unroll
        for (int mt = 0; mt < 2; ++mt) {
            for (int nt = 0; nt < ntm; ++nt) {
                float e[4];
#pragma unroll
                for (int r = 0; r < 4; ++r) {
                    float s = st[mt][nt][r];
                    if (last) {
                        int kg = kt * 64 + nt * 16 + lg * 4 + r;
                        int qg = qw + mt * 16 + lr;
                        if (kg > qg) s = -1e30f;
                    }
                    e[r] = __expf(s);
                    ls[mt] += e[r];
                }
                uint2 pk;
                pk.x = pack2bf(e[0], e[1]);
                pk.y = pack2bf(e[2], e[3]);
                *(uint2*)&lP[w][mt * 16 + lr][nt * 16 + lg * 4] = pk;
            }
            for (int nt = ntm; nt < kcm * 2; ++nt) {
                uint2 z; z.x = 0; z.y = 0;
                *(uint2*)&lP[w][mt * 16 + lr][nt * 16 + lg * 4] = z;
            }
        }

        // P as A-fragment (wave-private LDS round-trip, no barrier)
        bf16x8 pf[2][2];
#pragma unroll
        for (int mt = 0; mt < 2; ++mt)
            for (int kc = 0; kc < kcm; ++kc)
                pf[mt][kc] = *(const bf16x8*)&lP[w][mt * 16 + lr][kc * 32 + lg * 8];

#pragma unroll
        for (int mt = 0; mt < 2; ++mt)
#pragma unroll
            for (int nt = 0; nt < 4; ++nt)
                for (int kc = 0; kc < kcm; ++kc)
                    o[mt][nt] = __builtin_amdgcn_mfma_f32_16x16x32_bf16(pf[mt][kc], vf[nt][kc], o[mt][nt], 0, 0, 0);
    }

    // deferred row-sum reduction (lanes {lr, lr+16, lr+32, lr+48} hold partials for q=lr)
    float inv[2];
#pragma unroll
    for (int mt = 0; mt < 2; ++mt) {
        float s = ls[mt];
        s += __shfl_xor(s, 16);
        s += __shfl_xor(s, 32);
        inv[mt] = 1.0f / s;
    }

#pragma unroll
    for (int mt = 0; mt < 2; ++mt) {
        float iv[4];
#pragma unroll
        for (int r = 0; r < 4; ++r) iv[r] = __shfl(inv[mt], lg * 4 + r);
#pragma unroll
        for (int nt = 0; nt < 4; ++nt)
#pragma unroll
            for (int r = 0; r < 4; ++r) {
                int qrow = qw + mt * 16 + lg * 4 + r;
                int col = h * 64 + nt * 16 + lr;
                Y[((size_t)b * 1024 + qrow) * 384 + col] = f2bf(o[mt][nt][r] * iv[r]);
            }
    }
}

// ---------------- launcher ----------------

extern "C" void kernel_launch(void* const* d_in, const int* in_sizes, int n_in,
                              void* d_out, int out_size, void* d_ws, size_t ws_size,
                              hipStream_t stream)
{
    const float* x  = (const float*)d_in[0];
    const float* Wa = (const float*)d_in[1];
    const float* Wp = (const float*)d_in[2];
    const float* bp = (const float*)d_in[3];
    float* out = (float*)d_out;

    char* ws = (char*)d_ws;
    unsigned short* xb  = (unsigned short*)(ws);              // 25165824 B; reused as Y after attn
    unsigned short* WaT = (unsigned short*)(ws + 25165824);   // 884736 B
    unsigned short* WpT = (unsigned short*)(ws + 26050560);   // 294912 B
    unsigned short* Qb  = (unsigned short*)(ws + 26345472);   // 25165824 B
    unsigned short* Kb  = (unsigned short*)(ws + 51511296);   // 25165824 B
    unsigned short* Vtb = (unsigned short*)(ws + 76677120);   // 25165824 B

    k_cvt_bf16<<<12288, 256, 0, stream>>>(x, xb, 3145728);
    k_transpose_bf16<<<1728, 256, 0, stream>>>(Wa, WaT, 384, 1152);
    k_transpose_bf16<<<576, 256, 0, stream>>>(Wp, WpT, 384, 384);

    k_gemm<0><<<dim3(256, 9), 256, 0, stream>>>(xb, WaT, Qb, Kb, Vtb, nullptr, nullptr);
    k_attn<<<dim3(48, 32), 256, 0, stream>>>(Qb, Kb, Vtb, xb);
    k_gemm<1><<<dim3(256, 3), 256, 0, stream>>>(xb, WpT, nullptr, nullptr, nullptr, bp, out);
}

// Round 3
// 235.599 us; speedup vs baseline: 46.6729x; 46.6729x over previous
//
#include <hip/hip_runtime.h>
#include <hip/hip_bf16.h>

#define DEV __device__ __forceinline__

typedef __attribute__((ext_vector_type(4))) float f32x4;
typedef __bf16 bf16x8 __attribute__((ext_vector_type(8)));

static DEV unsigned short f2bf(float f) {
    union { float f; unsigned u; } x; x.f = f;
    unsigned r = x.u + 0x7fffu + ((x.u >> 16) & 1u);
    return (unsigned short)(r >> 16);
}

static DEV unsigned pack2bf(float a, float b) {
    return (unsigned)f2bf(a) | ((unsigned)f2bf(b) << 16);
}

static DEV f32x4 zero4() { f32x4 v; v[0] = 0.f; v[1] = 0.f; v[2] = 0.f; v[3] = 0.f; return v; }

// ---------------- conversion kernels ----------------

__global__ void k_cvt_bf16(const float* __restrict__ in, unsigned short* __restrict__ out, int n4) {
    int i = blockIdx.x * blockDim.x + threadIdx.x;
    if (i >= n4) return;
    float4 v = reinterpret_cast<const float4*>(in)[i];
    ushort4 o;
    o.x = f2bf(v.x); o.y = f2bf(v.y); o.z = f2bf(v.z); o.w = f2bf(v.w);
    reinterpret_cast<ushort4*>(out)[i] = o;
}

// in [K][N] f32 -> out [N][K] bf16
__global__ void k_transpose_bf16(const float* __restrict__ in, unsigned short* __restrict__ out, int K, int N) {
    int i = blockIdx.x * blockDim.x + threadIdx.x;
    if (i >= K * N) return;
    int n = i / K, k = i - n * K;
    out[i] = f2bf(in[(size_t)k * N + n]);
}

// ---------------- GEMM: C[M,N] = A[M,384] * B^T  (B stored [N][384]) ----------------

template <int EPI>
__global__ __launch_bounds__(256) void k_gemm(
    const unsigned short* __restrict__ A,
    const unsigned short* __restrict__ B,
    unsigned short* __restrict__ Qb, unsigned short* __restrict__ Kb, unsigned short* __restrict__ Vtb,
    const float* __restrict__ bias, float* __restrict__ Out)
{
    const int K = 384;
    __shared__ unsigned short lA[128][72];
    __shared__ unsigned short lB[128][72];

    int tid = threadIdx.x;
    int m0 = blockIdx.x * 128;
    int n0 = blockIdx.y * 128;
    int w = tid >> 6, lane = tid & 63;
    int wm = (w >> 1) * 64, wn = (w & 1) * 64;
    int lr = lane & 15, lg = lane >> 4;

    f32x4 acc[4][4];
#pragma unroll
    for (int i = 0; i < 4; i++)
#pragma unroll
        for (int j = 0; j < 4; j++) acc[i][j] = zero4();

    int srow = tid >> 3, scol = (tid & 7) * 8;

    for (int kb = 0; kb < K; kb += 64) {
        __syncthreads();
#pragma unroll
        for (int p = 0; p < 4; ++p) {
            int r = srow + p * 32;
            *(uint4*)&lA[r][scol] = *(const uint4*)&A[(size_t)(m0 + r) * K + kb + scol];
            *(uint4*)&lB[r][scol] = *(const uint4*)&B[(size_t)(n0 + r) * K + kb + scol];
        }
        __syncthreads();

        bf16x8 af[4][2], bfr[4][2];
#pragma unroll
        for (int kc = 0; kc < 2; ++kc) {
#pragma unroll
            for (int t = 0; t < 4; ++t) {
                af[t][kc]  = *(const bf16x8*)&lA[wm + t * 16 + lr][kc * 32 + lg * 8];
                bfr[t][kc] = *(const bf16x8*)&lB[wn + t * 16 + lr][kc * 32 + lg * 8];
            }
        }
#pragma unroll
        for (int kc = 0; kc < 2; ++kc)
#pragma unroll
            for (int mt = 0; mt < 4; ++mt)
#pragma unroll
                for (int nt = 0; nt < 4; ++nt)
                    acc[mt][nt] = __builtin_amdgcn_mfma_f32_16x16x32_bf16(af[mt][kc], bfr[nt][kc], acc[mt][nt], 0, 0, 0);
    }

#pragma unroll
    for (int mt = 0; mt < 4; ++mt) {
#pragma unroll
        for (int nt = 0; nt < 4; ++nt) {
#pragma unroll
            for (int r = 0; r < 4; ++r) {
                int row = m0 + wm + mt * 16 + lg * 4 + r;
                int col = n0 + wn + nt * 16 + lr;
                float v = acc[mt][nt][r];
                if (EPI == 0) {
                    int which = col / 384;
                    int c = col - which * 384;
                    int hh = c >> 6, d = c & 63;
                    int bb = row >> 10, t = row & 1023;
                    size_t bh = (size_t)bb * 6 + hh;
                    if (which == 0)      Qb[(bh * 1024 + t) * 64 + d] = f2bf(v * 0.125f);
                    else if (which == 1) Kb[(bh * 1024 + t) * 64 + d] = f2bf(v);
                    else                 Vtb[(bh * 64 + d) * 1024 + t] = f2bf(v);
                } else {
                    Out[(size_t)row * 384 + col] = v + bias[col];
                }
            }
        }
    }
}

// ---------------- flash attention, fixed-max, no block barriers ----------------
// All tile shapes are compile-time (rule #20: no runtime-indexed vector arrays).
// NTM = number of 16-wide k subtiles in this tile (2 or 4); MASK = causal mask.

template <int NTM, bool MASK>
static DEV void attn_step(
    const unsigned short* __restrict__ Kp,
    const unsigned short* __restrict__ Vt,
    size_t bT, int bh, int kt, int qw,
    const bf16x8 (&qf)[2][2], f32x4 (&o)[2][4], float (&ls)[2],
    unsigned short (&lPw)[32][72], int lr, int lg)
{
    constexpr int KCM = NTM / 2;

    bf16x8 kf[NTM][2];
#pragma unroll
    for (int nt = 0; nt < NTM; ++nt)
#pragma unroll
        for (int kc = 0; kc < 2; ++kc)
            kf[nt][kc] = *(const bf16x8*)&Kp[(bT + kt * 64 + nt * 16 + lr) * 64 + kc * 32 + lg * 8];

    bf16x8 vf[4][KCM];
#pragma unroll
    for (int nt = 0; nt < 4; ++nt)
#pragma unroll
        for (int kc = 0; kc < KCM; ++kc)
            vf[nt][kc] = *(const bf16x8*)&Vt[((size_t)bh * 64 + nt * 16 + lr) * 1024 + kt * 64 + kc * 32 + lg * 8];

    // S^T = K * Q^T : lane holds col=q(lr), rows=k(lg*4+r) per 16-k subtile
    f32x4 st[2][NTM];
#pragma unroll
    for (int mt = 0; mt < 2; ++mt)
#pragma unroll
        for (int nt = 0; nt < NTM; ++nt) st[mt][nt] = zero4();

#pragma unroll
    for (int kc = 0; kc < 2; ++kc)
#pragma unroll
        for (int mt = 0; mt < 2; ++mt)
#pragma unroll
            for (int nt = 0; nt < NTM; ++nt)
                st[mt][nt] = __builtin_amdgcn_mfma_f32_16x16x32_bf16(kf[nt][kc], qf[mt][kc], st[mt][nt], 0, 0, 0);

    // exp (fixed max), per-lane partial rowsum, pack bf16, vector LDS write
#pragma unroll
    for (int mt = 0; mt < 2; ++mt) {
#pragma unroll
        for (int nt = 0; nt < NTM; ++nt) {
            float e[4];
#pragma unroll
            for (int r = 0; r < 4; ++r) {
                float s = st[mt][nt][r];
                if (MASK) {
                    int kg = kt * 64 + nt * 16 + lg * 4 + r;
                    int qg = qw + mt * 16 + lr;
                    if (kg > qg) s = -1e30f;
                }
                e[r] = __expf(s);
                ls[mt] += e[r];
            }
            uint2 pk;
            pk.x = pack2bf(e[0], e[1]);
            pk.y = pack2bf(e[2], e[3]);
            *(uint2*)&lPw[mt * 16 + lr][nt * 16 + lg * 4] = pk;
        }
    }

    // P as A-fragment (wave-private LDS round-trip, no barrier)
    bf16x8 pf[2][KCM];
#pragma unroll
    for (int mt = 0; mt < 2; ++mt)
#pragma unroll
        for (int kc = 0; kc < KCM; ++kc)
            pf[mt][kc] = *(const bf16x8*)&lPw[mt * 16 + lr][kc * 32 + lg * 8];

#pragma unroll
    for (int mt = 0; mt < 2; ++mt)
#pragma unroll
        for (int nt = 0; nt < 4; ++nt)
#pragma unroll
            for (int kc = 0; kc < KCM; ++kc)
                o[mt][nt] = __builtin_amdgcn_mfma_f32_16x16x32_bf16(pf[mt][kc], vf[nt][kc], o[mt][nt], 0, 0, 0);
}

// grid (48 bh-groups, 32 qtiles); block 256 = 4 waves; wave w handles bh = bx*4+w,
// q-rows [qt*32, qt*32+32). K,V fragments read directly from global (L2-resident).
__global__ __launch_bounds__(256) void k_attn(
    const unsigned short* __restrict__ Q,
    const unsigned short* __restrict__ Kp,
    const unsigned short* __restrict__ Vt,
    unsigned short* __restrict__ Y)
{
    __shared__ unsigned short lP[4][32][72];

    const int tid = threadIdx.x;
    const int w = tid >> 6, lane = tid & 63;
    const int lr = lane & 15, lg = lane >> 4;
    const int qt = 31 - blockIdx.y;          // heaviest q-tiles dispatched first
    const int bh = blockIdx.x * 4 + w;
    const int b = bh / 6, h = bh - b * 6;
    const int qw = qt * 32;
    const size_t bT = (size_t)bh * 1024;

    bf16x8 qf[2][2];
#pragma unroll
    for (int mt = 0; mt < 2; ++mt)
#pragma unroll
        for (int kc = 0; kc < 2; ++kc)
            qf[mt][kc] = *(const bf16x8*)&Q[(bT + qw + mt * 16 + lr) * 64 + kc * 32 + lg * 8];

    f32x4 o[2][4];
    float ls[2] = {0.f, 0.f};
#pragma unroll
    for (int mt = 0; mt < 2; ++mt)
#pragma unroll
        for (int nt = 0; nt < 4; ++nt) o[mt][nt] = zero4();

    const int nkt = (qw >> 6) + 1;
    for (int kt = 0; kt < nkt - 1; ++kt)
        attn_step<4, false>(Kp, Vt, bT, bh, kt, qw, qf, o, ls, lP[w], lr, lg);

    if (qt & 1) attn_step<4, true>(Kp, Vt, bT, bh, nkt - 1, qw, qf, o, ls, lP[w], lr, lg);
    else        attn_step<2, true>(Kp, Vt, bT, bh, nkt - 1, qw, qf, o, ls, lP[w], lr, lg);

    // deferred row-sum reduction (lanes {lr, lr+16, lr+32, lr+48} hold partials for q=lr)
    float inv[2];
#pragma unroll
    for (int mt = 0; mt < 2; ++mt) {
        float s = ls[mt];
        s += __shfl_xor(s, 16);
        s += __shfl_xor(s, 32);
        inv[mt] = 1.0f / s;
    }

#pragma unroll
    for (int mt = 0; mt < 2; ++mt) {
        float iv[4];
#pragma unroll
        for (int r = 0; r < 4; ++r) iv[r] = __shfl(inv[mt], lg * 4 + r);
#pragma unroll
        for (int nt = 0; nt < 4; ++nt)
#pragma unroll
            for (int r = 0; r < 4; ++r) {
                int qrow = qw + mt * 16 + lg * 4 + r;
                int col = h * 64 + nt * 16 + lr;
                Y[((size_t)b * 1024 + qrow) * 384 + col] = f2bf(o[mt][nt][r] * iv[r]);
            }
    }
}

// ---------------- launcher ----------------

extern "C" void kernel_launch(void* const* d_in, const int* in_sizes, int n_in,
                              void* d_out, int out_size, void* d_ws, size_t ws_size,
                              hipStream_t stream)
{
    const float* x  = (const float*)d_in[0];
    const float* Wa = (const float*)d_in[1];
    const float* Wp = (const float*)d_in[2];
    const float* bp = (const float*)d_in[3];
    float* out = (float*)d_out;

    char* ws = (char*)d_ws;
    unsigned short* xb  = (unsigned short*)(ws);              // 25165824 B; reused as Y after attn
    unsigned short* WaT = (unsigned short*)(ws + 25165824);   // 884736 B
    unsigned short* WpT = (unsigned short*)(ws + 26050560);   // 294912 B
    unsigned short* Qb  = (unsigned short*)(ws + 26345472);   // 25165824 B
    unsigned short* Kb  = (unsigned short*)(ws + 51511296);   // 25165824 B
    unsigned short* Vtb = (unsigned short*)(ws + 76677120);   // 25165824 B

    k_cvt_bf16<<<12288, 256, 0, stream>>>(x, xb, 3145728);
    k_transpose_bf16<<<1728, 256, 0, stream>>>(Wa, WaT, 384, 1152);
    k_transpose_bf16<<<576, 256, 0, stream>>>(Wp, WpT, 384, 384);

    k_gemm<0><<<dim3(256, 9), 256, 0, stream>>>(xb, WaT, Qb, Kb, Vtb, nullptr, nullptr);
    k_attn<<<dim3(48, 32), 256, 0, stream>>>(Qb, Kb, Vtb, xb);
    k_gemm<1><<<dim3(256, 3), 256, 0, stream>>>(xb, WpT, nullptr, nullptr, nullptr, bp, out);
}

// Round 4
// 206.028 us; speedup vs baseline: 53.3719x; 1.1435x over previous
//
#include <hip/hip_runtime.h>
#include <hip/hip_bf16.h>

#define DEV __device__ __forceinline__

typedef __attribute__((ext_vector_type(4))) float f32x4;
typedef __bf16 bf16x8 __attribute__((ext_vector_type(8)));

static DEV unsigned short f2bf(float f) {
    union { float f; unsigned u; } x; x.f = f;
    unsigned r = x.u + 0x7fffu + ((x.u >> 16) & 1u);
    return (unsigned short)(r >> 16);
}

static DEV f32x4 zero4() { f32x4 v; v[0] = 0.f; v[1] = 0.f; v[2] = 0.f; v[3] = 0.f; return v; }

#define GL1(p) ((const __attribute__((address_space(1))) void*)(p))
#define LDS3(p) ((__attribute__((address_space(3))) void*)(p))

// ---------------- conversion kernels ----------------

__global__ void k_cvt_bf16(const float* __restrict__ in, unsigned short* __restrict__ out, int n4) {
    int i = blockIdx.x * blockDim.x + threadIdx.x;
    if (i >= n4) return;
    float4 v = reinterpret_cast<const float4*>(in)[i];
    ushort4 o;
    o.x = f2bf(v.x); o.y = f2bf(v.y); o.z = f2bf(v.z); o.w = f2bf(v.w);
    reinterpret_cast<ushort4*>(out)[i] = o;
}

// in [K][N] f32 -> out [N][K] bf16
__global__ void k_transpose_bf16(const float* __restrict__ in, unsigned short* __restrict__ out, int K, int N) {
    int i = blockIdx.x * blockDim.x + threadIdx.x;
    if (i >= K * N) return;
    int n = i / K, k = i - n * K;
    out[i] = f2bf(in[(size_t)k * N + n]);
}

// ---------------- GEMM: C[M,N] = A[M,384] * B^T  (B stored [N][384]) ----------------
// m97-style: global_load_lds width-16 staging into linear LDS, 2-barrier K-loop.

template <int EPI>
__global__ __launch_bounds__(256) void k_gemm(
    const unsigned short* __restrict__ A,
    const unsigned short* __restrict__ B,
    unsigned short* __restrict__ Qb, unsigned short* __restrict__ Kb, unsigned short* __restrict__ Vtb,
    const float* __restrict__ bias, float* __restrict__ Out)
{
    const int K = 384;
    __shared__ unsigned short lA[128][64];
    __shared__ unsigned short lB[128][64];

    int tid = threadIdx.x;
    int m0 = blockIdx.x * 128;
    int n0 = blockIdx.y * 128;
    int w = tid >> 6, lane = tid & 63;
    int wm = (w >> 1) * 64, wn = (w & 1) * 64;
    int lr = lane & 15, lg = lane >> 4;

    f32x4 acc[4][4];
#pragma unroll
    for (int i = 0; i < 4; i++)
#pragma unroll
        for (int j = 0; j < 4; j++) acc[i][j] = zero4();

    // staging: per wave-instruction, lane l covers row (chunk*8 + l>>3), 16B granule (l&7)
    const int lrow = lane >> 3;
    const int lcol = (lane & 7) * 8;

    for (int kb = 0; kb < K; kb += 64) {
        __syncthreads();   // prior ds_reads done (lgkmcnt drained by barrier)
#pragma unroll
        for (int c = 0; c < 4; ++c) {
            int rb = (w * 4 + c) * 8;
            __builtin_amdgcn_global_load_lds(GL1(&A[(size_t)(m0 + rb + lrow) * K + kb + lcol]),
                                             LDS3(&lA[rb][0]), 16, 0, 0);
            __builtin_amdgcn_global_load_lds(GL1(&B[(size_t)(n0 + rb + lrow) * K + kb + lcol]),
                                             LDS3(&lB[rb][0]), 16, 0, 0);
        }
        __syncthreads();   // compiler drains vmcnt(0) before s_barrier -> tiles ready

        bf16x8 af[4][2], bfr[4][2];
#pragma unroll
        for (int kc = 0; kc < 2; ++kc) {
#pragma unroll
            for (int t = 0; t < 4; ++t) {
                af[t][kc]  = *(const bf16x8*)&lA[wm + t * 16 + lr][kc * 32 + lg * 8];
                bfr[t][kc] = *(const bf16x8*)&lB[wn + t * 16 + lr][kc * 32 + lg * 8];
            }
        }
#pragma unroll
        for (int kc = 0; kc < 2; ++kc)
#pragma unroll
            for (int mt = 0; mt < 4; ++mt)
#pragma unroll
                for (int nt = 0; nt < 4; ++nt)
                    acc[mt][nt] = __builtin_amdgcn_mfma_f32_16x16x32_bf16(af[mt][kc], bfr[nt][kc], acc[mt][nt], 0, 0, 0);
    }

#pragma unroll
    for (int mt = 0; mt < 4; ++mt) {
#pragma unroll
        for (int nt = 0; nt < 4; ++nt) {
#pragma unroll
            for (int r = 0; r < 4; ++r) {
                int row = m0 + wm + mt * 16 + lg * 4 + r;
                int col = n0 + wn + nt * 16 + lr;
                float v = acc[mt][nt][r];
                if (EPI == 0) {
                    int which = col / 384;
                    int c = col - which * 384;
                    int hh = c >> 6, d = c & 63;
                    int bb = row >> 10, t = row & 1023;
                    size_t bh = (size_t)bb * 6 + hh;
                    // Q pre-scaled by 1/sqrt(64) * log2(e) for exp2-domain softmax
                    if (which == 0)      Qb[(bh * 1024 + t) * 64 + d] = f2bf(v * 0.18033688f);
                    else if (which == 1) Kb[(bh * 1024 + t) * 64 + d] = f2bf(v);
                    else                 Vtb[(bh * 64 + d) * 1024 + t] = f2bf(v);
                } else {
                    Out[(size_t)row * 384 + col] = v + bias[col];
                }
            }
        }
    }
}

// ---------------- flash attention, fixed-max (exp2 domain), no block barriers ----
// One qtile step on pre-loaded K/V fragments. All shapes compile-time.

template <int NTM, bool MASK>
static DEV void attn_tile(
    const bf16x8 (&kf)[4][2], const bf16x8 (&vf)[4][2],
    const bf16x8 (&qf)[2][2], f32x4 (&o)[2][4], float (&ls)[2],
    unsigned short (&lPw)[32][72], int kt, int qw, int lr, int lg)
{
    constexpr int KCM = NTM / 2;

    // S^T = K * Q^T : lane holds col=q(lr), rows=k(lg*4+r) per 16-k subtile
    f32x4 st[2][NTM];
#pragma unroll
    for (int mt = 0; mt < 2; ++mt)
#pragma unroll
        for (int nt = 0; nt < NTM; ++nt) st[mt][nt] = zero4();

#pragma unroll
    for (int kc = 0; kc < 2; ++kc)
#pragma unroll
        for (int mt = 0; mt < 2; ++mt)
#pragma unroll
            for (int nt = 0; nt < NTM; ++nt)
                st[mt][nt] = __builtin_amdgcn_mfma_f32_16x16x32_bf16(kf[nt][kc], qf[mt][kc], st[mt][nt], 0, 0, 0);

    // exp2 (fixed max), per-lane partial rowsum, native bf16 pack, vector LDS write
#pragma unroll
    for (int mt = 0; mt < 2; ++mt) {
#pragma unroll
        for (int nt = 0; nt < NTM; ++nt) {
            union { __bf16 h[4]; uint2 u; } pk;
#pragma unroll
            for (int r = 0; r < 4; ++r) {
                float e = __builtin_amdgcn_exp2f(st[mt][nt][r]);
                if (MASK) {
                    int kg = kt * 64 + nt * 16 + lg * 4 + r;
                    int qg = qw + mt * 16 + lr;
                    if (kg > qg) e = 0.f;
                }
                ls[mt] += e;
                pk.h[r] = (__bf16)e;
            }
            *(uint2*)&lPw[mt * 16 + lr][nt * 16 + lg * 4] = pk.u;
        }
    }

    // P as A-fragment (wave-private LDS round-trip, no barrier)
    bf16x8 pf[2][KCM];
#pragma unroll
    for (int mt = 0; mt < 2; ++mt)
#pragma unroll
        for (int kc = 0; kc < KCM; ++kc)
            pf[mt][kc] = *(const bf16x8*)&lPw[mt * 16 + lr][kc * 32 + lg * 8];

#pragma unroll
    for (int mt = 0; mt < 2; ++mt)
#pragma unroll
        for (int nt = 0; nt < 4; ++nt)
#pragma unroll
            for (int kc = 0; kc < KCM; ++kc)
                o[mt][nt] = __builtin_amdgcn_mfma_f32_16x16x32_bf16(pf[mt][kc], vf[nt][kc], o[mt][nt], 0, 0, 0);
}

static DEV void attn_tail(bool odd,
    const bf16x8 (&kf)[4][2], const bf16x8 (&vf)[4][2],
    const bf16x8 (&qf)[2][2], f32x4 (&o)[2][4], float (&ls)[2],
    unsigned short (&lPw)[32][72], int kt, int qw, int lr, int lg)
{
    if (odd) attn_tile<4, true>(kf, vf, qf, o, ls, lPw, kt, qw, lr, lg);
    else     attn_tile<2, true>(kf, vf, qf, o, ls, lPw, kt, qw, lr, lg);
}

static DEV void attn_out(const f32x4 (&o)[2][4], const float (&ls)[2],
                         int qw, int b, int h, int lr, int lg,
                         unsigned short* __restrict__ Y)
{
    float inv[2];
#pragma unroll
    for (int mt = 0; mt < 2; ++mt) {
        float s = ls[mt];
        s += __shfl_xor(s, 16);
        s += __shfl_xor(s, 32);
        inv[mt] = 1.0f / s;
    }
#pragma unroll
    for (int mt = 0; mt < 2; ++mt) {
        float iv[4];
#pragma unroll
        for (int r = 0; r < 4; ++r) iv[r] = __shfl(inv[mt], lg * 4 + r);
#pragma unroll
        for (int nt = 0; nt < 4; ++nt)
#pragma unroll
            for (int r = 0; r < 4; ++r) {
                int qrow = qw + mt * 16 + lg * 4 + r;
                int col = h * 64 + nt * 16 + lr;
                Y[((size_t)b * 1024 + qrow) * 384 + col] = f2bf(o[mt][nt][r] * iv[r]);
            }
    }
}

// grid (48 bh-groups, 16 qtile-pairs); block 256 = 4 waves; wave w handles bh=bx*4+w,
// q-tiles qtA=16+p and qtB=15-p (uniform 17 tile-steps per wave; K/V loads shared).
__global__ __launch_bounds__(256) void k_attn(
    const unsigned short* __restrict__ Q,
    const unsigned short* __restrict__ Kp,
    const unsigned short* __restrict__ Vt,
    unsigned short* __restrict__ Y)
{
    __shared__ unsigned short lP[4][2][32][72];

    const int tid = threadIdx.x;
    const int w = tid >> 6, lane = tid & 63;
    const int lr = lane & 15, lg = lane >> 4;
    const int p = blockIdx.y;
    const int qtA = 16 + p, qtB = 15 - p;
    const int bh = blockIdx.x * 4 + w;
    const int b = bh / 6, h = bh - b * 6;
    const int qwA = qtA * 32, qwB = qtB * 32;
    const int nktA = qtA / 2 + 1, nktB = qtB / 2 + 1;
    const size_t bT = (size_t)bh * 1024;

    bf16x8 qfA[2][2], qfB[2][2];
#pragma unroll
    for (int mt = 0; mt < 2; ++mt)
#pragma unroll
        for (int kc = 0; kc < 2; ++kc) {
            qfA[mt][kc] = *(const bf16x8*)&Q[(bT + qwA + mt * 16 + lr) * 64 + kc * 32 + lg * 8];
            qfB[mt][kc] = *(const bf16x8*)&Q[(bT + qwB + mt * 16 + lr) * 64 + kc * 32 + lg * 8];
        }

    f32x4 oA[2][4], oB[2][4];
    float lsA[2] = {0.f, 0.f}, lsB[2] = {0.f, 0.f};
#pragma unroll
    for (int mt = 0; mt < 2; ++mt)
#pragma unroll
        for (int nt = 0; nt < 4; ++nt) { oA[mt][nt] = zero4(); oB[mt][nt] = zero4(); }

    for (int kt = 0; kt < nktA; ++kt) {
        bf16x8 kf[4][2], vf[4][2];
#pragma unroll
        for (int nt = 0; nt < 4; ++nt)
#pragma unroll
            for (int kc = 0; kc < 2; ++kc) {
                kf[nt][kc] = *(const bf16x8*)&Kp[(bT + kt * 64 + nt * 16 + lr) * 64 + kc * 32 + lg * 8];
                vf[nt][kc] = *(const bf16x8*)&Vt[((size_t)bh * 64 + nt * 16 + lr) * 1024 + kt * 64 + kc * 32 + lg * 8];
            }

        if (kt == nktA - 1)
            attn_tail(qtA & 1, kf, vf, qfA, oA, lsA, lP[w][0], kt, qwA, lr, lg);
        else
            attn_tile<4, false>(kf, vf, qfA, oA, lsA, lP[w][0], kt, qwA, lr, lg);

        if (kt < nktB) {
            if (kt == nktB - 1)
                attn_tail(qtB & 1, kf, vf, qfB, oB, lsB, lP[w][1], kt, qwB, lr, lg);
            else
                attn_tile<4, false>(kf, vf, qfB, oB, lsB, lP[w][1], kt, qwB, lr, lg);
        }
    }

    attn_out(oA, lsA, qwA, b, h, lr, lg, Y);
    attn_out(oB, lsB, qwB, b, h, lr, lg, Y);
}

// ---------------- launcher ----------------

extern "C" void kernel_launch(void* const* d_in, const int* in_sizes, int n_in,
                              void* d_out, int out_size, void* d_ws, size_t ws_size,
                              hipStream_t stream)
{
    const float* x  = (const float*)d_in[0];
    const float* Wa = (const float*)d_in[1];
    const float* Wp = (const float*)d_in[2];
    const float* bp = (const float*)d_in[3];
    float* out = (float*)d_out;

    char* ws = (char*)d_ws;
    unsigned short* xb  = (unsigned short*)(ws);              // 25165824 B; reused as Y after attn
    unsigned short* WaT = (unsigned short*)(ws + 25165824);   // 884736 B
    unsigned short* WpT = (unsigned short*)(ws + 26050560);   // 294912 B
    unsigned short* Qb  = (unsigned short*)(ws + 26345472);   // 25165824 B
    unsigned short* Kb  = (unsigned short*)(ws + 51511296);   // 25165824 B
    unsigned short* Vtb = (unsigned short*)(ws + 76677120);   // 25165824 B

    k_cvt_bf16<<<12288, 256, 0, stream>>>(x, xb, 3145728);
    k_transpose_bf16<<<1728, 256, 0, stream>>>(Wa, WaT, 384, 1152);
    k_transpose_bf16<<<576, 256, 0, stream>>>(Wp, WpT, 384, 384);

    k_gemm<0><<<dim3(256, 9), 256, 0, stream>>>(xb, WaT, Qb, Kb, Vtb, nullptr, nullptr);
    k_attn<<<dim3(48, 16), 256, 0, stream>>>(Qb, Kb, Vtb, xb);
    k_gemm<1><<<dim3(256, 3), 256, 0, stream>>>(xb, WpT, nullptr, nullptr, nullptr, bp, out);
}